// Round 1
// baseline (113.345 us; speedup 1.0000x reference)
//
#include <hip/hip_runtime.h>

// Based linear attention via exact degree-2 kernel expansion, chunked scan.
// B=1, H=16, S=4096, D=16.  phi(s)=1+s+0.5 s^2, s = (q.k)/sqrt(D), causal.
// out_i = [v0 + q'.S1 + 0.5 (q'xq').S2 + intra] / [z0 + q'.z1 + 0.5 q' z2 q' + intra_z + 1e-6]
// States summed over keys j < i (exclusive chunk prefix + exact intra-chunk).

namespace {
constexpr int H = 16;
constexpr int S = 4096;
constexpr int D = 16;
constexpr int C = 128;        // chunk length
constexpr int NC = S / C;     // 32 chunks
// per-(head,chunk) state block, floats
constexpr int OFF_S2 = 0;     // [256][16]  S2[d1*16+d2][dv] = sum k_d1 k_d2 v_dv
constexpr int OFF_S1 = 4096;  // [16][16]   S1[d1][dv]       = sum k_d1 v_dv
constexpr int OFF_Z2 = 4352;  // [256]      z2[d1*16+d2]     = sum k_d1 k_d2
constexpr int OFF_Z1 = 4608;  // [16]       z1[d1]           = sum k_d1
constexpr int OFF_V0 = 4624;  // [16]       v0[dv]           = sum v_dv
constexpr int STATE = 4640;
}

// ---------------- kernel 1: per-chunk state ----------------
__global__ __launch_bounds__(256) void based_chunk_state(
    const float* __restrict__ kg_, const float* __restrict__ vg_,
    float* __restrict__ ws, int hb) {
  const int c = blockIdx.x;
  const int hl = blockIdx.y;
  const int h = hb + hl;
  const int tid = threadIdx.x;
  __shared__ float ks[C * D];
  __shared__ float vs[C * D];
  const float* kg = kg_ + ((size_t)h * S + (size_t)c * C) * D;
  const float* vg = vg_ + ((size_t)h * S + (size_t)c * C) * D;
#pragma unroll
  for (int i = 0; i < (C * D / 4) / 256; ++i) {
    int idx = tid + i * 256;
    reinterpret_cast<float4*>(ks)[idx] = reinterpret_cast<const float4*>(kg)[idx];
    reinterpret_cast<float4*>(vs)[idx] = reinterpret_cast<const float4*>(vg)[idx];
  }
  __syncthreads();

  const int d1 = tid >> 4;
  const int d2 = tid & 15;
  float s2a[16];
#pragma unroll
  for (int i = 0; i < 16; ++i) s2a[i] = 0.f;
  float z2a = 0.f, s1a = 0.f, z1a = 0.f, v0a = 0.f;

  for (int j = 0; j < C; ++j) {
    const float kd1 = ks[j * 16 + d1];
    const float kd2 = ks[j * 16 + d2];
    const float vd2 = vs[j * 16 + d2];
    const float w = kd1 * kd2;
    z2a += w;
    s1a = fmaf(kd1, vd2, s1a);
    v0a += vd2;
    z1a += kd1;
    const float4 va = *reinterpret_cast<const float4*>(&vs[j * 16 + 0]);
    const float4 vb = *reinterpret_cast<const float4*>(&vs[j * 16 + 4]);
    const float4 vc = *reinterpret_cast<const float4*>(&vs[j * 16 + 8]);
    const float4 vd = *reinterpret_cast<const float4*>(&vs[j * 16 + 12]);
    s2a[0]  = fmaf(w, va.x, s2a[0]);
    s2a[1]  = fmaf(w, va.y, s2a[1]);
    s2a[2]  = fmaf(w, va.z, s2a[2]);
    s2a[3]  = fmaf(w, va.w, s2a[3]);
    s2a[4]  = fmaf(w, vb.x, s2a[4]);
    s2a[5]  = fmaf(w, vb.y, s2a[5]);
    s2a[6]  = fmaf(w, vb.z, s2a[6]);
    s2a[7]  = fmaf(w, vb.w, s2a[7]);
    s2a[8]  = fmaf(w, vc.x, s2a[8]);
    s2a[9]  = fmaf(w, vc.y, s2a[9]);
    s2a[10] = fmaf(w, vc.z, s2a[10]);
    s2a[11] = fmaf(w, vc.w, s2a[11]);
    s2a[12] = fmaf(w, vd.x, s2a[12]);
    s2a[13] = fmaf(w, vd.y, s2a[13]);
    s2a[14] = fmaf(w, vd.z, s2a[14]);
    s2a[15] = fmaf(w, vd.w, s2a[15]);
  }

  float* st = ws + ((size_t)hl * NC + c) * STATE;
#pragma unroll
  for (int i = 0; i < 4; ++i) {
    float4 t = make_float4(s2a[4 * i + 0], s2a[4 * i + 1], s2a[4 * i + 2], s2a[4 * i + 3]);
    *reinterpret_cast<float4*>(&st[OFF_S2 + tid * 16 + 4 * i]) = t;
  }
  st[OFF_Z2 + tid] = z2a;
  st[OFF_S1 + tid] = s1a;               // thread (d1,d2) holds S1[d1][dv=d2]
  if (d2 == 0) st[OFF_Z1 + d1] = z1a;
  if (d1 == 0) st[OFF_V0 + d2] = v0a;
}

// ---------------- kernel 2: exclusive prefix scan over chunks ----------------
__global__ __launch_bounds__(256) void based_scan(float* __restrict__ ws) {
  const int e = blockIdx.x * 256 + threadIdx.x;
  if (e >= STATE) return;
  const int hl = blockIdx.y;
  float* p = ws + (size_t)hl * NC * STATE + e;
  float vals[NC];
#pragma unroll
  for (int c = 0; c < NC; ++c) vals[c] = p[(size_t)c * STATE];
  float run = 0.f;
#pragma unroll
  for (int c = 0; c < NC; ++c) {
    const float t = vals[c];
    p[(size_t)c * STATE] = run;
    run += t;
  }
}

// ---------------- kernel 3: inter (state apply) + exact intra ----------------
__device__ __forceinline__ float dot16(const float* __restrict__ qr,
                                       const float4 a, const float4 b,
                                       const float4 cc, const float4 d) {
  float s0 = fmaf(qr[0], a.x, qr[1] * a.y);
  s0 = fmaf(qr[2], a.z, s0);
  s0 = fmaf(qr[3], a.w, s0);
  float s1 = fmaf(qr[4], b.x, qr[5] * b.y);
  s1 = fmaf(qr[6], b.z, s1);
  s1 = fmaf(qr[7], b.w, s1);
  float s2 = fmaf(qr[8], cc.x, qr[9] * cc.y);
  s2 = fmaf(qr[10], cc.z, s2);
  s2 = fmaf(qr[11], cc.w, s2);
  float s3 = fmaf(qr[12], d.x, qr[13] * d.y);
  s3 = fmaf(qr[14], d.z, s3);
  s3 = fmaf(qr[15], d.w, s3);
  return (s0 + s1) + (s2 + s3);
}

__global__ __launch_bounds__(256) void based_out(
    const float* __restrict__ qg_, const float* __restrict__ kg_,
    const float* __restrict__ vg_, const float* __restrict__ ws,
    float* __restrict__ outg_, int hb) {
  const int c = blockIdx.x;
  const int hl = blockIdx.y;
  const int h = hb + hl;
  const int tid = threadIdx.x;
  __shared__ float qs[C * D];
  __shared__ float ksh[C * D];
  __shared__ float vsh[C * D];
  __shared__ float st[STATE];

  const float* qg = qg_ + ((size_t)h * S + (size_t)c * C) * D;
  const float* kg = kg_ + ((size_t)h * S + (size_t)c * C) * D;
  const float* vg = vg_ + ((size_t)h * S + (size_t)c * C) * D;
  const float* stg = ws + ((size_t)hl * NC + c) * STATE;

#pragma unroll
  for (int i = 0; i < (C * D / 4) / 256; ++i) {
    int idx = tid + i * 256;
    float4 t = reinterpret_cast<const float4*>(qg)[idx];
    t.x *= 0.25f; t.y *= 0.25f; t.z *= 0.25f; t.w *= 0.25f;  // scale = 1/sqrt(D)
    reinterpret_cast<float4*>(qs)[idx] = t;
    reinterpret_cast<float4*>(ksh)[idx] = reinterpret_cast<const float4*>(kg)[idx];
    reinterpret_cast<float4*>(vsh)[idx] = reinterpret_cast<const float4*>(vg)[idx];
  }
  for (int i = tid; i < STATE / 4; i += 256) {
    reinterpret_cast<float4*>(st)[i] = reinterpret_cast<const float4*>(stg)[i];
  }
  __syncthreads();

  const int pr = tid >> 2;       // 0..63: query pair (pr, C-1-pr)
  const int dvq = tid & 3;       // dv quarter
  const int iA = pr;
  const int iB = C - 1 - pr;

  float qA[16], qB[16];
#pragma unroll
  for (int ii = 0; ii < 4; ++ii) {
    const float4 a = *reinterpret_cast<const float4*>(&qs[iA * 16 + 4 * ii]);
    qA[4 * ii + 0] = a.x; qA[4 * ii + 1] = a.y; qA[4 * ii + 2] = a.z; qA[4 * ii + 3] = a.w;
    const float4 b = *reinterpret_cast<const float4*>(&qs[iB * 16 + 4 * ii]);
    qB[4 * ii + 0] = b.x; qB[4 * ii + 1] = b.y; qB[4 * ii + 2] = b.z; qB[4 * ii + 3] = b.w;
  }

  // ---- inter: constant + v0 / z0 terms
  float zA = (float)(c * C), zB = (float)(c * C);
  float4 yA = *reinterpret_cast<const float4*>(&st[OFF_V0 + dvq * 4]);
  float4 yB = yA;

  // ---- inter: S1 / z1 (linear term)
  for (int d1 = 0; d1 < 16; ++d1) {
    const float aA = qs[iA * 16 + d1];
    const float aB = qs[iB * 16 + d1];
    const float4 s1v = *reinterpret_cast<const float4*>(&st[OFF_S1 + d1 * 16 + dvq * 4]);
    const float rz1 = st[OFF_Z1 + d1];
    yA.x = fmaf(aA, s1v.x, yA.x); yA.y = fmaf(aA, s1v.y, yA.y);
    yA.z = fmaf(aA, s1v.z, yA.z); yA.w = fmaf(aA, s1v.w, yA.w);
    zA = fmaf(aA, rz1, zA);
    yB.x = fmaf(aB, s1v.x, yB.x); yB.y = fmaf(aB, s1v.y, yB.y);
    yB.z = fmaf(aB, s1v.z, yB.z); yB.w = fmaf(aB, s1v.w, yB.w);
    zB = fmaf(aB, rz1, zB);
  }

  // ---- inter: S2 / z2 (quadratic term, 0.5 folded into w)
  for (int d1 = 0; d1 < 16; ++d1) {
    const float ahA = 0.5f * qs[iA * 16 + d1];
    const float ahB = 0.5f * qs[iB * 16 + d1];
#pragma unroll
    for (int d2 = 0; d2 < 16; ++d2) {
      const int p = d1 * 16 + d2;
      const float4 s2v = *reinterpret_cast<const float4*>(&st[OFF_S2 + p * 16 + dvq * 4]);
      const float rz2 = st[OFF_Z2 + p];
      const float wA = ahA * qA[d2];
      const float wB = ahB * qB[d2];
      yA.x = fmaf(wA, s2v.x, yA.x); yA.y = fmaf(wA, s2v.y, yA.y);
      yA.z = fmaf(wA, s2v.z, yA.z); yA.w = fmaf(wA, s2v.w, yA.w);
      zA = fmaf(wA, rz2, zA);
      yB.x = fmaf(wB, s2v.x, yB.x); yB.y = fmaf(wB, s2v.y, yB.y);
      yB.z = fmaf(wB, s2v.z, yB.z); yB.w = fmaf(wB, s2v.w, yB.w);
      zB = fmaf(wB, rz2, zB);
    }
  }

  // ---- intra: exact causal. loop1: j<=pr serves BOTH queries unpredicated
  // (j<=pr<=63<=C-1-pr). loop2: pr<j<=C-1-pr serves only query B. No masks.
  for (int j = 0; j <= pr; ++j) {
    const float4 k0 = *reinterpret_cast<const float4*>(&ksh[j * 16 + 0]);
    const float4 k1 = *reinterpret_cast<const float4*>(&ksh[j * 16 + 4]);
    const float4 k2 = *reinterpret_cast<const float4*>(&ksh[j * 16 + 8]);
    const float4 k3 = *reinterpret_cast<const float4*>(&ksh[j * 16 + 12]);
    const float4 vv = *reinterpret_cast<const float4*>(&vsh[j * 16 + dvq * 4]);
    const float sA = dot16(qA, k0, k1, k2, k3);
    const float sB = dot16(qB, k0, k1, k2, k3);
    const float pA = fmaf(sA, fmaf(0.5f, sA, 1.f), 1.f);
    const float pB = fmaf(sB, fmaf(0.5f, sB, 1.f), 1.f);
    yA.x = fmaf(pA, vv.x, yA.x); yA.y = fmaf(pA, vv.y, yA.y);
    yA.z = fmaf(pA, vv.z, yA.z); yA.w = fmaf(pA, vv.w, yA.w);
    zA += pA;
    yB.x = fmaf(pB, vv.x, yB.x); yB.y = fmaf(pB, vv.y, yB.y);
    yB.z = fmaf(pB, vv.z, yB.z); yB.w = fmaf(pB, vv.w, yB.w);
    zB += pB;
  }
  for (int j = pr + 1; j <= C - 1 - pr; ++j) {
    const float4 k0 = *reinterpret_cast<const float4*>(&ksh[j * 16 + 0]);
    const float4 k1 = *reinterpret_cast<const float4*>(&ksh[j * 16 + 4]);
    const float4 k2 = *reinterpret_cast<const float4*>(&ksh[j * 16 + 8]);
    const float4 k3 = *reinterpret_cast<const float4*>(&ksh[j * 16 + 12]);
    const float4 vv = *reinterpret_cast<const float4*>(&vsh[j * 16 + dvq * 4]);
    const float sB = dot16(qB, k0, k1, k2, k3);
    const float pB = fmaf(sB, fmaf(0.5f, sB, 1.f), 1.f);
    yB.x = fmaf(pB, vv.x, yB.x); yB.y = fmaf(pB, vv.y, yB.y);
    yB.z = fmaf(pB, vv.z, yB.z); yB.w = fmaf(pB, vv.w, yB.w);
    zB += pB;
  }

  // ---- store
  float* outg = outg_ + ((size_t)h * S + (size_t)c * C) * D;
  const float invA = 1.0f / (zA + 1e-6f);
  const float invB = 1.0f / (zB + 1e-6f);
  float4 oA = make_float4(yA.x * invA, yA.y * invA, yA.z * invA, yA.w * invA);
  float4 oB = make_float4(yB.x * invB, yB.y * invB, yB.z * invB, yB.w * invB);
  reinterpret_cast<float4*>(outg)[iA * 4 + dvq] = oA;
  reinterpret_cast<float4*>(outg)[iB * 4 + dvq] = oB;
}

extern "C" void kernel_launch(void* const* d_in, const int* in_sizes, int n_in,
                              void* d_out, int out_size, void* d_ws, size_t ws_size,
                              hipStream_t stream) {
  (void)in_sizes; (void)n_in; (void)out_size;
  const float* q = (const float*)d_in[0];
  const float* k = (const float*)d_in[1];
  const float* v = (const float*)d_in[2];
  float* out = (float*)d_out;
  float* ws = (float*)d_ws;

  // Workspace: NC*STATE floats per head (~594 KB). Process as many heads per
  // pass as fit; full fit needs ~9.1 MB.
  const size_t per_head = (size_t)NC * STATE * sizeof(float);
  int hp = (int)(ws_size / per_head);
  if (hp < 1) hp = 1;
  if (hp > H) hp = H;

  for (int hb = 0; hb < H; hb += hp) {
    const int hn = (H - hb < hp) ? (H - hb) : hp;
    hipLaunchKernelGGL(based_chunk_state, dim3(NC, hn), dim3(256), 0, stream,
                       k, v, ws, hb);
    hipLaunchKernelGGL(based_scan, dim3((STATE + 255) / 256, hn), dim3(256), 0,
                       stream, ws);
    hipLaunchKernelGGL(based_out, dim3(NC, hn), dim3(256), 0, stream,
                       q, k, v, ws, out, hb);
  }
}

// Round 4
// 100.321 us; speedup vs baseline: 1.1298x; 1.1298x over previous
//
#include <hip/hip_runtime.h>

// Based linear attention via exact degree-2 kernel expansion, chunked scan.
// B=1, H=16, S=4096, D=16.  phi(s)=1+s+0.5 s^2, s=(q.k)/4, causal, normalized.
// S2 state stored triangular (symmetric): 136 rows of 16, halves K3 apply.

namespace {
constexpr int H = 16;
constexpr int S = 4096;
constexpr int D = 16;
constexpr int C = 128;        // chunk length
constexpr int NC = S / C;     // 32 chunks
constexpr int NP = 136;       // # pairs d1<=d2
// per-(head,chunk) state block, floats
constexpr int OFF_S2 = 0;             // [136][16]  S2[tri(d1,d2)][dv] = sum k_d1 k_d2 v_dv
constexpr int OFF_S1 = NP * 16;       // 2176: [16][16] S1[d1][dv] = sum k_d1 v_dv
constexpr int OFF_Z2 = OFF_S1 + 256;  // 2432: [136]  z2[t] = sum k_d1 k_d2
constexpr int OFF_Z1 = OFF_Z2 + NP;   // 2568: [16]
constexpr int OFF_V0 = OFF_Z1 + 16;   // 2584: [16]
constexpr int STATE  = OFF_V0 + 16;   // 2600

__device__ __forceinline__ constexpr int tri(int d1, int d2) {
  return d1 * 16 + d2 - (d1 * (d1 + 1)) / 2;   // valid for d1<=d2
}

// sum across the 4 lanes of a quad via DPP (pure VALU, no LDS pipe)
__device__ __forceinline__ float qsum4(float x) {
  int a = __builtin_amdgcn_mov_dpp(__float_as_int(x), 0xB1, 0xF, 0xF, true); // xor 1
  x += __int_as_float(a);
  int b = __builtin_amdgcn_mov_dpp(__float_as_int(x), 0x4E, 0xF, 0xF, true); // xor 2
  x += __int_as_float(b);
  return x;
}
}

// ---------------- kernel 1: per-chunk state ----------------
__global__ __launch_bounds__(256) void based_chunk_state(
    const float* __restrict__ kg_, const float* __restrict__ vg_,
    float* __restrict__ ws, int hb) {
  const int c = blockIdx.x;
  const int hl = blockIdx.y;
  const int h = hb + hl;
  const int tid = threadIdx.x;
  __shared__ float ks[C * D];
  __shared__ float vs[C * D];
  const float* kg = kg_ + ((size_t)h * S + (size_t)c * C) * D;
  const float* vg = vg_ + ((size_t)h * S + (size_t)c * C) * D;
#pragma unroll
  for (int i = 0; i < 2; ++i) {
    int idx = tid + i * 256;
    reinterpret_cast<float4*>(ks)[idx] = reinterpret_cast<const float4*>(kg)[idx];
    reinterpret_cast<float4*>(vs)[idx] = reinterpret_cast<const float4*>(vg)[idx];
  }
  __syncthreads();

  const int d1 = tid >> 4;
  const int d2 = tid & 15;
  float s2a[16];
#pragma unroll
  for (int i = 0; i < 16; ++i) s2a[i] = 0.f;
  float z2a = 0.f, s1a = 0.f, z1a = 0.f, v0a = 0.f;

#pragma unroll 2
  for (int j = 0; j < C; ++j) {
    // v row quarters: wave-uniform address -> scalar/L1 path, off the LDS pipe
    const float4 va = *reinterpret_cast<const float4*>(vg + j * 16 + 0);
    const float4 vb = *reinterpret_cast<const float4*>(vg + j * 16 + 4);
    const float4 vc = *reinterpret_cast<const float4*>(vg + j * 16 + 8);
    const float4 vd = *reinterpret_cast<const float4*>(vg + j * 16 + 12);
    const float kd1 = ks[j * 16 + d1];
    const float kd2 = ks[j * 16 + d2];
    const float vd2l = vs[j * 16 + d2];
    const float w = kd1 * kd2;
    z2a += w;
    z1a += kd1;
    v0a += vd2l;
    s1a = fmaf(kd1, vd2l, s1a);
    s2a[0]  = fmaf(w, va.x, s2a[0]);
    s2a[1]  = fmaf(w, va.y, s2a[1]);
    s2a[2]  = fmaf(w, va.z, s2a[2]);
    s2a[3]  = fmaf(w, va.w, s2a[3]);
    s2a[4]  = fmaf(w, vb.x, s2a[4]);
    s2a[5]  = fmaf(w, vb.y, s2a[5]);
    s2a[6]  = fmaf(w, vb.z, s2a[6]);
    s2a[7]  = fmaf(w, vb.w, s2a[7]);
    s2a[8]  = fmaf(w, vc.x, s2a[8]);
    s2a[9]  = fmaf(w, vc.y, s2a[9]);
    s2a[10] = fmaf(w, vc.z, s2a[10]);
    s2a[11] = fmaf(w, vc.w, s2a[11]);
    s2a[12] = fmaf(w, vd.x, s2a[12]);
    s2a[13] = fmaf(w, vd.y, s2a[13]);
    s2a[14] = fmaf(w, vd.z, s2a[14]);
    s2a[15] = fmaf(w, vd.w, s2a[15]);
  }

  float* st = ws + ((size_t)hl * NC + c) * STATE;
  if (d1 <= d2) {
    const int t = d1 * 16 + d2 - (d1 * (d1 + 1)) / 2;
#pragma unroll
    for (int i = 0; i < 4; ++i) {
      float4 tv = make_float4(s2a[4 * i + 0], s2a[4 * i + 1], s2a[4 * i + 2], s2a[4 * i + 3]);
      *reinterpret_cast<float4*>(&st[OFF_S2 + t * 16 + 4 * i]) = tv;
    }
    st[OFF_Z2 + t] = z2a;
  }
  st[OFF_S1 + tid] = s1a;               // thread (d1, dv=d2)
  if (d2 == 0) st[OFF_Z1 + d1] = z1a;
  if (d1 == 0) st[OFF_V0 + d2] = v0a;
}

// ---------------- kernel 2: exclusive prefix scan over chunks ----------------
__global__ __launch_bounds__(256) void based_scan(float* __restrict__ ws) {
  const int e = blockIdx.x * 256 + threadIdx.x;
  if (e >= STATE) return;
  const int hl = blockIdx.y;
  float* p = ws + (size_t)hl * NC * STATE + e;
  float vals[NC];
#pragma unroll
  for (int c = 0; c < NC; ++c) vals[c] = p[(size_t)c * STATE];
  float run = 0.f;
#pragma unroll
  for (int c = 0; c < NC; ++c) {
    const float t = vals[c];
    p[(size_t)c * STATE] = run;
    run += t;
  }
}

// ---------------- kernel 3: inter (state apply) + exact intra ----------------
__global__ __launch_bounds__(256) void based_out(
    const float* __restrict__ qg_, const float* __restrict__ kg_,
    const float* __restrict__ vg_, const float* __restrict__ ws,
    float* __restrict__ outg_, int hb) {
  const int c = blockIdx.x;
  const int hl = blockIdx.y;
  const int h = hb + hl;
  const int tid = threadIdx.x;
  __shared__ float qs[C * D];
  __shared__ float ksh[C * D];
  __shared__ float vsh[C * D];
  __shared__ float st[STATE];

  const float* qg = qg_ + ((size_t)h * S + (size_t)c * C) * D;
  const float* kg = kg_ + ((size_t)h * S + (size_t)c * C) * D;
  const float* vg = vg_ + ((size_t)h * S + (size_t)c * C) * D;
  const float* stg = ws + ((size_t)hl * NC + c) * STATE;

#pragma unroll
  for (int i = 0; i < 2; ++i) {
    int idx = tid + i * 256;
    float4 t = reinterpret_cast<const float4*>(qg)[idx];
    t.x *= 0.25f; t.y *= 0.25f; t.z *= 0.25f; t.w *= 0.25f;  // scale = 1/sqrt(16)
    reinterpret_cast<float4*>(qs)[idx] = t;
    reinterpret_cast<float4*>(ksh)[idx] = reinterpret_cast<const float4*>(kg)[idx];
    reinterpret_cast<float4*>(vsh)[idx] = reinterpret_cast<const float4*>(vg)[idx];
  }
  for (int i = tid; i < STATE / 4; i += 256) {
    // STATE=2600 -> 650 float4s
    reinterpret_cast<float4*>(st)[i] = reinterpret_cast<const float4*>(stg)[i];
  }
  __syncthreads();

  const int pr = tid >> 2;       // 0..63: query pair (pr, C-1-pr)
  const int dvq = tid & 3;       // dv quarter
  const int iA = pr;
  const int iB = C - 1 - pr;

  float qA[16], qB[16];
#pragma unroll
  for (int ii = 0; ii < 4; ++ii) {
    const float4 a = *reinterpret_cast<const float4*>(&qs[iA * 16 + 4 * ii]);
    qA[4 * ii + 0] = a.x; qA[4 * ii + 1] = a.y; qA[4 * ii + 2] = a.z; qA[4 * ii + 3] = a.w;
    const float4 b = *reinterpret_cast<const float4*>(&qs[iB * 16 + 4 * ii]);
    qB[4 * ii + 0] = b.x; qB[4 * ii + 1] = b.y; qB[4 * ii + 2] = b.z; qB[4 * ii + 3] = b.w;
  }
  // quarter copies for the intra dot (named scalars: compile-time register indices)
  const float qa0 = qs[iA * 16 + dvq * 4 + 0];
  const float qa1 = qs[iA * 16 + dvq * 4 + 1];
  const float qa2 = qs[iA * 16 + dvq * 4 + 2];
  const float qa3 = qs[iA * 16 + dvq * 4 + 3];
  const float qb0 = qs[iB * 16 + dvq * 4 + 0];
  const float qb1 = qs[iB * 16 + dvq * 4 + 1];
  const float qb2 = qs[iB * 16 + dvq * 4 + 2];
  const float qb3 = qs[iB * 16 + dvq * 4 + 3];

  // ---- inter: constant + v0 / z0
  float zA = (float)(c * C), zB = (float)(c * C);
  float4 yA = *reinterpret_cast<const float4*>(&st[OFF_V0 + dvq * 4]);
  float4 yB = yA;

  // ---- inter: S1 / z1 (linear term)
#pragma unroll
  for (int d1 = 0; d1 < 16; ++d1) {
    const float aA = qA[d1];
    const float aB = qB[d1];
    const float4 s1v = *reinterpret_cast<const float4*>(&st[OFF_S1 + d1 * 16 + dvq * 4]);
    const float rz1 = st[OFF_Z1 + d1];
    yA.x = fmaf(aA, s1v.x, yA.x); yA.y = fmaf(aA, s1v.y, yA.y);
    yA.z = fmaf(aA, s1v.z, yA.z); yA.w = fmaf(aA, s1v.w, yA.w);
    zA = fmaf(aA, rz1, zA);
    yB.x = fmaf(aB, s1v.x, yB.x); yB.y = fmaf(aB, s1v.y, yB.y);
    yB.z = fmaf(aB, s1v.z, yB.z); yB.w = fmaf(aB, s1v.w, yB.w);
    zB = fmaf(aB, rz1, zB);
  }

  // ---- inter: S2 / z2 triangular (136 iters; off-diag weight q1*q2, diag 0.5*q^2)
#pragma unroll
  for (int d1 = 0; d1 < 16; ++d1) {
    const float a1A = qA[d1];
    const float a1B = qB[d1];
    {
      const int t = tri(d1, d1);
      const float4 s2v = *reinterpret_cast<const float4*>(&st[OFF_S2 + t * 16 + dvq * 4]);
      const float rz2 = st[OFF_Z2 + t];
      const float wA = 0.5f * a1A * a1A;
      const float wB = 0.5f * a1B * a1B;
      yA.x = fmaf(wA, s2v.x, yA.x); yA.y = fmaf(wA, s2v.y, yA.y);
      yA.z = fmaf(wA, s2v.z, yA.z); yA.w = fmaf(wA, s2v.w, yA.w);
      zA = fmaf(wA, rz2, zA);
      yB.x = fmaf(wB, s2v.x, yB.x); yB.y = fmaf(wB, s2v.y, yB.y);
      yB.z = fmaf(wB, s2v.z, yB.z); yB.w = fmaf(wB, s2v.w, yB.w);
      zB = fmaf(wB, rz2, zB);
    }
#pragma unroll
    for (int d2 = d1 + 1; d2 < 16; ++d2) {
      const int t = tri(d1, d2);
      const float4 s2v = *reinterpret_cast<const float4*>(&st[OFF_S2 + t * 16 + dvq * 4]);
      const float rz2 = st[OFF_Z2 + t];
      const float wA = a1A * qA[d2];
      const float wB = a1B * qB[d2];
      yA.x = fmaf(wA, s2v.x, yA.x); yA.y = fmaf(wA, s2v.y, yA.y);
      yA.z = fmaf(wA, s2v.z, yA.z); yA.w = fmaf(wA, s2v.w, yA.w);
      zA = fmaf(wA, rz2, zA);
      yB.x = fmaf(wB, s2v.x, yB.x); yB.y = fmaf(wB, s2v.y, yB.y);
      yB.z = fmaf(wB, s2v.z, yB.z); yB.w = fmaf(wB, s2v.w, yB.w);
      zB = fmaf(wB, rz2, zB);
    }
  }

  // ---- intra: exact causal. loop1: j<=pr serves BOTH queries; loop2: B only.
  // Quad-butterfly dot: each dvq lane does a quarter-dot, DPP-sum across quad.
  for (int j = 0; j <= pr; ++j) {
    const float4 kq = *reinterpret_cast<const float4*>(&ksh[j * 16 + dvq * 4]);
    const float4 vv = *reinterpret_cast<const float4*>(&vsh[j * 16 + dvq * 4]);
    float sA = fmaf(qa0, kq.x, qa1 * kq.y);
    sA = fmaf(qa2, kq.z, sA);
    sA = fmaf(qa3, kq.w, sA);
    float sB = fmaf(qb0, kq.x, qb1 * kq.y);
    sB = fmaf(qb2, kq.z, sB);
    sB = fmaf(qb3, kq.w, sB);
    sA = qsum4(sA);
    sB = qsum4(sB);
    const float pA = fmaf(sA, fmaf(0.5f, sA, 1.f), 1.f);
    const float pB = fmaf(sB, fmaf(0.5f, sB, 1.f), 1.f);
    yA.x = fmaf(pA, vv.x, yA.x); yA.y = fmaf(pA, vv.y, yA.y);
    yA.z = fmaf(pA, vv.z, yA.z); yA.w = fmaf(pA, vv.w, yA.w);
    zA += pA;
    yB.x = fmaf(pB, vv.x, yB.x); yB.y = fmaf(pB, vv.y, yB.y);
    yB.z = fmaf(pB, vv.z, yB.z); yB.w = fmaf(pB, vv.w, yB.w);
    zB += pB;
  }
  for (int j = pr + 1; j <= C - 1 - pr; ++j) {
    const float4 kq = *reinterpret_cast<const float4*>(&ksh[j * 16 + dvq * 4]);
    const float4 vv = *reinterpret_cast<const float4*>(&vsh[j * 16 + dvq * 4]);
    float sB = fmaf(qb0, kq.x, qb1 * kq.y);
    sB = fmaf(qb2, kq.z, sB);
    sB = fmaf(qb3, kq.w, sB);
    sB = qsum4(sB);
    const float pB = fmaf(sB, fmaf(0.5f, sB, 1.f), 1.f);
    yB.x = fmaf(pB, vv.x, yB.x); yB.y = fmaf(pB, vv.y, yB.y);
    yB.z = fmaf(pB, vv.z, yB.z); yB.w = fmaf(pB, vv.w, yB.w);
    zB += pB;
  }

  // ---- store
  float* outg = outg_ + ((size_t)h * S + (size_t)c * C) * D;
  const float invA = 1.0f / (zA + 1e-6f);
  const float invB = 1.0f / (zB + 1e-6f);
  float4 oA = make_float4(yA.x * invA, yA.y * invA, yA.z * invA, yA.w * invA);
  float4 oB = make_float4(yB.x * invB, yB.y * invB, yB.z * invB, yB.w * invB);
  reinterpret_cast<float4*>(outg)[iA * 4 + dvq] = oA;
  reinterpret_cast<float4*>(outg)[iB * 4 + dvq] = oB;
}

extern "C" void kernel_launch(void* const* d_in, const int* in_sizes, int n_in,
                              void* d_out, int out_size, void* d_ws, size_t ws_size,
                              hipStream_t stream) {
  (void)in_sizes; (void)n_in; (void)out_size;
  const float* q = (const float*)d_in[0];
  const float* k = (const float*)d_in[1];
  const float* v = (const float*)d_in[2];
  float* out = (float*)d_out;
  float* ws = (float*)d_ws;

  // Workspace: NC*STATE floats per head (~333 KB); all 16 heads need ~5.3 MB.
  const size_t per_head = (size_t)NC * STATE * sizeof(float);
  int hp = (int)(ws_size / per_head);
  if (hp < 1) hp = 1;
  if (hp > H) hp = H;

  for (int hb = 0; hb < H; hb += hp) {
    const int hn = (H - hb < hp) ? (H - hb) : hp;
    hipLaunchKernelGGL(based_chunk_state, dim3(NC, hn), dim3(256), 0, stream,
                       k, v, ws, hb);
    hipLaunchKernelGGL(based_scan, dim3((STATE + 255) / 256, hn), dim3(256), 0,
                       stream, ws);
    hipLaunchKernelGGL(based_out, dim3(NC, hn), dim3(256), 0, stream,
                       q, k, v, ws, out, hb);
  }
}

// Round 6
// 100.235 us; speedup vs baseline: 1.1308x; 1.0009x over previous
//
#include <hip/hip_runtime.h>

// Based linear attention via exact degree-2 kernel expansion, chunked scan.
// B=1, H=16, S=4096, D=16.  phi(s)=1+s+0.5 s^2, s=(q.k)/4, causal, normalized.
// S2 state stored triangular (symmetric): 136 rows of 16, halves K3 apply.
// PROVEN R4 configuration (100.3 us, absmax 9.77e-4). Cooperative fusion
// reverted: raced on cross-XCD state visibility (R5 post-mortem).

namespace {
constexpr int H = 16;
constexpr int S = 4096;
constexpr int D = 16;
constexpr int C = 128;        // chunk length
constexpr int NC = S / C;     // 32 chunks
constexpr int NP = 136;       // # pairs d1<=d2
// per-(head,chunk) state block, floats
constexpr int OFF_S2 = 0;             // [136][16]  S2[tri(d1,d2)][dv] = sum k_d1 k_d2 v_dv
constexpr int OFF_S1 = NP * 16;       // 2176: [16][16] S1[d1][dv] = sum k_d1 v_dv
constexpr int OFF_Z2 = OFF_S1 + 256;  // 2432: [136]  z2[t] = sum k_d1 k_d2
constexpr int OFF_Z1 = OFF_Z2 + NP;   // 2568: [16]
constexpr int OFF_V0 = OFF_Z1 + 16;   // 2584: [16]
constexpr int STATE  = OFF_V0 + 16;   // 2600

__device__ __forceinline__ constexpr int tri(int d1, int d2) {
  return d1 * 16 + d2 - (d1 * (d1 + 1)) / 2;   // valid for d1<=d2
}

// sum across the 4 lanes of a quad via DPP (pure VALU, no LDS pipe)
__device__ __forceinline__ float qsum4(float x) {
  int a = __builtin_amdgcn_mov_dpp(__float_as_int(x), 0xB1, 0xF, 0xF, true); // xor 1
  x += __int_as_float(a);
  int b = __builtin_amdgcn_mov_dpp(__float_as_int(x), 0x4E, 0xF, 0xF, true); // xor 2
  x += __int_as_float(b);
  return x;
}
}

// ---------------- kernel 1: per-chunk state ----------------
__global__ __launch_bounds__(256) void based_chunk_state(
    const float* __restrict__ kg_, const float* __restrict__ vg_,
    float* __restrict__ ws, int hb) {
  const int c = blockIdx.x;
  const int hl = blockIdx.y;
  const int h = hb + hl;
  const int tid = threadIdx.x;
  __shared__ float ks[C * D];
  __shared__ float vs[C * D];
  const float* kg = kg_ + ((size_t)h * S + (size_t)c * C) * D;
  const float* vg = vg_ + ((size_t)h * S + (size_t)c * C) * D;
#pragma unroll
  for (int i = 0; i < 2; ++i) {
    int idx = tid + i * 256;
    reinterpret_cast<float4*>(ks)[idx] = reinterpret_cast<const float4*>(kg)[idx];
    reinterpret_cast<float4*>(vs)[idx] = reinterpret_cast<const float4*>(vg)[idx];
  }
  __syncthreads();

  const int d1 = tid >> 4;
  const int d2 = tid & 15;
  float s2a[16];
#pragma unroll
  for (int i = 0; i < 16; ++i) s2a[i] = 0.f;
  float z2a = 0.f, s1a = 0.f, z1a = 0.f, v0a = 0.f;

#pragma unroll 2
  for (int j = 0; j < C; ++j) {
    // v row quarters: wave-uniform address -> scalar/L1 path, off the LDS pipe
    const float4 va = *reinterpret_cast<const float4*>(vg + j * 16 + 0);
    const float4 vb = *reinterpret_cast<const float4*>(vg + j * 16 + 4);
    const float4 vc = *reinterpret_cast<const float4*>(vg + j * 16 + 8);
    const float4 vd = *reinterpret_cast<const float4*>(vg + j * 16 + 12);
    const float kd1 = ks[j * 16 + d1];
    const float kd2 = ks[j * 16 + d2];
    const float vd2l = vs[j * 16 + d2];
    const float w = kd1 * kd2;
    z2a += w;
    z1a += kd1;
    v0a += vd2l;
    s1a = fmaf(kd1, vd2l, s1a);
    s2a[0]  = fmaf(w, va.x, s2a[0]);
    s2a[1]  = fmaf(w, va.y, s2a[1]);
    s2a[2]  = fmaf(w, va.z, s2a[2]);
    s2a[3]  = fmaf(w, va.w, s2a[3]);
    s2a[4]  = fmaf(w, vb.x, s2a[4]);
    s2a[5]  = fmaf(w, vb.y, s2a[5]);
    s2a[6]  = fmaf(w, vb.z, s2a[6]);
    s2a[7]  = fmaf(w, vb.w, s2a[7]);
    s2a[8]  = fmaf(w, vc.x, s2a[8]);
    s2a[9]  = fmaf(w, vc.y, s2a[9]);
    s2a[10] = fmaf(w, vc.z, s2a[10]);
    s2a[11] = fmaf(w, vc.w, s2a[11]);
    s2a[12] = fmaf(w, vd.x, s2a[12]);
    s2a[13] = fmaf(w, vd.y, s2a[13]);
    s2a[14] = fmaf(w, vd.z, s2a[14]);
    s2a[15] = fmaf(w, vd.w, s2a[15]);
  }

  float* st = ws + ((size_t)hl * NC + c) * STATE;
  if (d1 <= d2) {
    const int t = d1 * 16 + d2 - (d1 * (d1 + 1)) / 2;
#pragma unroll
    for (int i = 0; i < 4; ++i) {
      float4 tv = make_float4(s2a[4 * i + 0], s2a[4 * i + 1], s2a[4 * i + 2], s2a[4 * i + 3]);
      *reinterpret_cast<float4*>(&st[OFF_S2 + t * 16 + 4 * i]) = tv;
    }
    st[OFF_Z2 + t] = z2a;
  }
  st[OFF_S1 + tid] = s1a;               // thread (d1, dv=d2)
  if (d2 == 0) st[OFF_Z1 + d1] = z1a;
  if (d1 == 0) st[OFF_V0 + d2] = v0a;
}

// ---------------- kernel 2: exclusive prefix scan over chunks ----------------
__global__ __launch_bounds__(256) void based_scan(float* __restrict__ ws) {
  const int e = blockIdx.x * 256 + threadIdx.x;
  if (e >= STATE) return;
  const int hl = blockIdx.y;
  float* p = ws + (size_t)hl * NC * STATE + e;
  float vals[NC];
#pragma unroll
  for (int c = 0; c < NC; ++c) vals[c] = p[(size_t)c * STATE];
  float run = 0.f;
#pragma unroll
  for (int c = 0; c < NC; ++c) {
    const float t = vals[c];
    p[(size_t)c * STATE] = run;
    run += t;
  }
}

// ---------------- kernel 3: inter (state apply) + exact intra ----------------
__global__ __launch_bounds__(256) void based_out(
    const float* __restrict__ qg_, const float* __restrict__ kg_,
    const float* __restrict__ vg_, const float* __restrict__ ws,
    float* __restrict__ outg_, int hb) {
  const int c = blockIdx.x;
  const int hl = blockIdx.y;
  const int h = hb + hl;
  const int tid = threadIdx.x;
  __shared__ float qs[C * D];
  __shared__ float ksh[C * D];
  __shared__ float vsh[C * D];
  __shared__ float st[STATE];

  const float* qg = qg_ + ((size_t)h * S + (size_t)c * C) * D;
  const float* kg = kg_ + ((size_t)h * S + (size_t)c * C) * D;
  const float* vg = vg_ + ((size_t)h * S + (size_t)c * C) * D;
  const float* stg = ws + ((size_t)hl * NC + c) * STATE;

#pragma unroll
  for (int i = 0; i < 2; ++i) {
    int idx = tid + i * 256;
    float4 t = reinterpret_cast<const float4*>(qg)[idx];
    t.x *= 0.25f; t.y *= 0.25f; t.z *= 0.25f; t.w *= 0.25f;  // scale = 1/sqrt(16)
    reinterpret_cast<float4*>(qs)[idx] = t;
    reinterpret_cast<float4*>(ksh)[idx] = reinterpret_cast<const float4*>(kg)[idx];
    reinterpret_cast<float4*>(vsh)[idx] = reinterpret_cast<const float4*>(vg)[idx];
  }
  for (int i = tid; i < STATE / 4; i += 256) {
    // STATE=2600 -> 650 float4s
    reinterpret_cast<float4*>(st)[i] = reinterpret_cast<const float4*>(stg)[i];
  }
  __syncthreads();

  const int pr = tid >> 2;       // 0..63: query pair (pr, C-1-pr)
  const int dvq = tid & 3;       // dv quarter
  const int iA = pr;
  const int iB = C - 1 - pr;

  float qA[16], qB[16];
#pragma unroll
  for (int ii = 0; ii < 4; ++ii) {
    const float4 a = *reinterpret_cast<const float4*>(&qs[iA * 16 + 4 * ii]);
    qA[4 * ii + 0] = a.x; qA[4 * ii + 1] = a.y; qA[4 * ii + 2] = a.z; qA[4 * ii + 3] = a.w;
    const float4 b = *reinterpret_cast<const float4*>(&qs[iB * 16 + 4 * ii]);
    qB[4 * ii + 0] = b.x; qB[4 * ii + 1] = b.y; qB[4 * ii + 2] = b.z; qB[4 * ii + 3] = b.w;
  }
  // quarter copies for the intra dot (named scalars: compile-time register indices)
  const float qa0 = qA[dvq * 4 + 0], qa1 = qA[dvq * 4 + 1];
  const float qa2 = qA[dvq * 4 + 2], qa3 = qA[dvq * 4 + 3];
  const float qb0 = qB[dvq * 4 + 0], qb1 = qB[dvq * 4 + 1];
  const float qb2 = qB[dvq * 4 + 2], qb3 = qB[dvq * 4 + 3];

  // ---- inter: constant + v0 / z0
  float zA = (float)(c * C), zB = (float)(c * C);
  float4 yA = *reinterpret_cast<const float4*>(&st[OFF_V0 + dvq * 4]);
  float4 yB = yA;

  // ---- inter: S1 / z1 (linear term)
#pragma unroll
  for (int d1 = 0; d1 < 16; ++d1) {
    const float aA = qA[d1];
    const float aB = qB[d1];
    const float4 s1v = *reinterpret_cast<const float4*>(&st[OFF_S1 + d1 * 16 + dvq * 4]);
    const float rz1 = st[OFF_Z1 + d1];
    yA.x = fmaf(aA, s1v.x, yA.x); yA.y = fmaf(aA, s1v.y, yA.y);
    yA.z = fmaf(aA, s1v.z, yA.z); yA.w = fmaf(aA, s1v.w, yA.w);
    zA = fmaf(aA, rz1, zA);
    yB.x = fmaf(aB, s1v.x, yB.x); yB.y = fmaf(aB, s1v.y, yB.y);
    yB.z = fmaf(aB, s1v.z, yB.z); yB.w = fmaf(aB, s1v.w, yB.w);
    zB = fmaf(aB, rz1, zB);
  }

  // ---- inter: S2 / z2 triangular (136 iters; off-diag weight q1*q2, diag 0.5*q^2)
#pragma unroll
  for (int d1 = 0; d1 < 16; ++d1) {
    const float a1A = qA[d1];
    const float a1B = qB[d1];
    {
      const int t = tri(d1, d1);
      const float4 s2v = *reinterpret_cast<const float4*>(&st[OFF_S2 + t * 16 + dvq * 4]);
      const float rz2 = st[OFF_Z2 + t];
      const float wA = 0.5f * a1A * a1A;
      const float wB = 0.5f * a1B * a1B;
      yA.x = fmaf(wA, s2v.x, yA.x); yA.y = fmaf(wA, s2v.y, yA.y);
      yA.z = fmaf(wA, s2v.z, yA.z); yA.w = fmaf(wA, s2v.w, yA.w);
      zA = fmaf(wA, rz2, zA);
      yB.x = fmaf(wB, s2v.x, yB.x); yB.y = fmaf(wB, s2v.y, yB.y);
      yB.z = fmaf(wB, s2v.z, yB.z); yB.w = fmaf(wB, s2v.w, yB.w);
      zB = fmaf(wB, rz2, zB);
    }
#pragma unroll
    for (int d2 = d1 + 1; d2 < 16; ++d2) {
      const int t = tri(d1, d2);
      const float4 s2v = *reinterpret_cast<const float4*>(&st[OFF_S2 + t * 16 + dvq * 4]);
      const float rz2 = st[OFF_Z2 + t];
      const float wA = a1A * qA[d2];
      const float wB = a1B * qB[d2];
      yA.x = fmaf(wA, s2v.x, yA.x); yA.y = fmaf(wA, s2v.y, yA.y);
      yA.z = fmaf(wA, s2v.z, yA.z); yA.w = fmaf(wA, s2v.w, yA.w);
      zA = fmaf(wA, rz2, zA);
      yB.x = fmaf(wB, s2v.x, yB.x); yB.y = fmaf(wB, s2v.y, yB.y);
      yB.z = fmaf(wB, s2v.z, yB.z); yB.w = fmaf(wB, s2v.w, yB.w);
      zB = fmaf(wB, rz2, zB);
    }
  }

  // ---- intra: exact causal. loop1: j<=pr serves BOTH queries; loop2: B only.
  // Quad-butterfly dot: each dvq lane does a quarter-dot, DPP-sum across quad.
  for (int j = 0; j <= pr; ++j) {
    const float4 kq = *reinterpret_cast<const float4*>(&ksh[j * 16 + dvq * 4]);
    const float4 vv = *reinterpret_cast<const float4*>(&vsh[j * 16 + dvq * 4]);
    float sA = fmaf(qa0, kq.x, qa1 * kq.y);
    sA = fmaf(qa2, kq.z, sA);
    sA = fmaf(qa3, kq.w, sA);
    float sB = fmaf(qb0, kq.x, qb1 * kq.y);
    sB = fmaf(qb2, kq.z, sB);
    sB = fmaf(qb3, kq.w, sB);
    sA = qsum4(sA);
    sB = qsum4(sB);
    const float pA = fmaf(sA, fmaf(0.5f, sA, 1.f), 1.f);
    const float pB = fmaf(sB, fmaf(0.5f, sB, 1.f), 1.f);
    yA.x = fmaf(pA, vv.x, yA.x); yA.y = fmaf(pA, vv.y, yA.y);
    yA.z = fmaf(pA, vv.z, yA.z); yA.w = fmaf(pA, vv.w, yA.w);
    zA += pA;
    yB.x = fmaf(pB, vv.x, yB.x); yB.y = fmaf(pB, vv.y, yB.y);
    yB.z = fmaf(pB, vv.z, yB.z); yB.w = fmaf(pB, vv.w, yB.w);
    zB += pB;
  }
  for (int j = pr + 1; j <= C - 1 - pr; ++j) {
    const float4 kq = *reinterpret_cast<const float4*>(&ksh[j * 16 + dvq * 4]);
    const float4 vv = *reinterpret_cast<const float4*>(&vsh[j * 16 + dvq * 4]);
    float sB = fmaf(qb0, kq.x, qb1 * kq.y);
    sB = fmaf(qb2, kq.z, sB);
    sB = fmaf(qb3, kq.w, sB);
    sB = qsum4(sB);
    const float pB = fmaf(sB, fmaf(0.5f, sB, 1.f), 1.f);
    yB.x = fmaf(pB, vv.x, yB.x); yB.y = fmaf(pB, vv.y, yB.y);
    yB.z = fmaf(pB, vv.z, yB.z); yB.w = fmaf(pB, vv.w, yB.w);
    zB += pB;
  }

  // ---- store
  float* outg = outg_ + ((size_t)h * S + (size_t)c * C) * D;
  const float invA = 1.0f / (zA + 1e-6f);
  const float invB = 1.0f / (zB + 1e-6f);
  float4 oA = make_float4(yA.x * invA, yA.y * invA, yA.z * invA, yA.w * invA);
  float4 oB = make_float4(yB.x * invB, yB.y * invB, yB.z * invB, yB.w * invB);
  reinterpret_cast<float4*>(outg)[iA * 4 + dvq] = oA;
  reinterpret_cast<float4*>(outg)[iB * 4 + dvq] = oB;
}

extern "C" void kernel_launch(void* const* d_in, const int* in_sizes, int n_in,
                              void* d_out, int out_size, void* d_ws, size_t ws_size,
                              hipStream_t stream) {
  (void)in_sizes; (void)n_in; (void)out_size;
  const float* q = (const float*)d_in[0];
  const float* k = (const float*)d_in[1];
  const float* v = (const float*)d_in[2];
  float* out = (float*)d_out;
  float* ws = (float*)d_ws;

  // Workspace: NC*STATE floats per head (~333 KB); all 16 heads need ~5.3 MB.
  const size_t per_head = (size_t)NC * STATE * sizeof(float);
  int hp = (int)(ws_size / per_head);
  if (hp < 1) hp = 1;
  if (hp > H) hp = H;

  for (int hb = 0; hb < H; hb += hp) {
    const int hn = (H - hb < hp) ? (H - hb) : hp;
    hipLaunchKernelGGL(based_chunk_state, dim3(NC, hn), dim3(256), 0, stream,
                       k, v, ws, hb);
    hipLaunchKernelGGL(based_scan, dim3((STATE + 255) / 256, hn), dim3(256), 0,
                       stream, ws);
    hipLaunchKernelGGL(based_out, dim3(NC, hn), dim3(256), 0, stream,
                       q, k, v, ws, out, hb);
  }
}